// Round 1
// baseline (4226.608 us; speedup 1.0000x reference)
//
#include <hip/hip_runtime.h>
#include <hip/hip_bf16.h>
#include <cstdint>

typedef unsigned int u32;
typedef unsigned short u16;
typedef __bf16 bf16x8 __attribute__((ext_vector_type(8)));
typedef float f32x4 __attribute__((ext_vector_type(4)));
typedef u16 u16x8 __attribute__((ext_vector_type(8)));

#define T_STEPS 512
#define NGRP 4            // batch groups (16 batches each)
#define GQ 16             // blocks per group (each owns 16 h-dims)
#define CTR_STRIDE 16     // u32 per (grp,step) counter line (64B)

#define CTR_U32_PER_LAYER (NGRP * 513 * CTR_STRIDE)
#define HBUF_OFF_BYTES (2 * CTR_U32_PER_LAYER * 4)
#define HBUF_U16_PER_LAYER (2 * NGRP * 16 * 256)   // [parity][grp][b][k]
#define HS0_OFF_BYTES (1u << 20)

__device__ __forceinline__ float sigm(float z) { return 1.f / (1.f + __expf(-z)); }
__device__ __forceinline__ float tanh_(float z) { return 1.f - 2.f / (__expf(2.f * z) + 1.f); }
__device__ __forceinline__ u16 f2bf(float f) {
    union { __bf16 b; u16 u; } v; v.b = (__bf16)f; return v.u;
}

// One persistent kernel per layer. Grid = 64 blocks (4 groups x 16), 256 threads (4 waves).
// Block (grp,q): batches [16*grp,16*grp+16), h-dims [16*q,16*q+16).
// Wave w owns dims [4w,4w+4) x all 4 gates => one 16-wide MFMA N-tile per wave,
// elementwise is wave-local through a private D_lds region (no extra barrier).
template <int KX, bool L0>
__global__ __launch_bounds__(256, 1) void lstm_rec(
    const float* __restrict__ xf,   // layer0 input x [64][512][128] f32
    const u16* __restrict__ xb,     // layer1 input hs0 [512][64][256] bf16 bits
    const float* __restrict__ W,    // [1024][256+KX] f32 (cols: [h | x])
    const float* __restrict__ bias, // [1024]
    u32* __restrict__ ctr,          // [grp][513] counters, stride 16 u32
    u16* __restrict__ hbuf,         // [2][grp][16][256] bf16 bits
    u16* __restrict__ hs0,          // layer0 output sequence (bf16 bits)
    float* __restrict__ out)        // 81920 f32
{
    constexpr int K = 256 + KX;
    constexpr int NHF = 8;          // h-part k-tiles (K=32 each)
    constexpr int NXF = KX / 32;    // x-part k-tiles
    constexpr int LDA = K + 8;      // u16 elems per A_lds row (pad kills bank conflicts)

    __shared__ u16 A_lds[16 * LDA];
    __shared__ float D_lds[4 * 16 * 17];  // per-wave region: wave*272 + n*17 + m
    __shared__ u16 h_slice[16 * 16];

    const int tid = threadIdx.x;
    const int wave = tid >> 6;
    const int lane = tid & 63;
    const int g = lane >> 4;
    const int n = lane & 15;
    const int bid = blockIdx.x;
    const int grp = bid >> 4;
    const int q = bid & 15;

    // ---- weights -> register B-fragments (one-time) ----
    // N-tile column n -> gate a = n>>2, local dim dd = n&3; wave w covers dims 4w..4w+3.
    const int a_gate = n >> 2;
    const int dd = n & 3;
    const int wrow = a_gate * 256 + q * 16 + (wave << 2) + dd;
    bf16x8 wfrag[K / 32];
    {
        const float* Wr = W + (long)wrow * K;
#pragma unroll
        for (int kt = 0; kt < K / 32; ++kt) {
            const float* p = Wr + kt * 32 + g * 8;
            float4 lo = *(const float4*)p;
            float4 hi = *(const float4*)(p + 4);
            bf16x8 f;
            f[0] = (__bf16)lo.x; f[1] = (__bf16)lo.y; f[2] = (__bf16)lo.z; f[3] = (__bf16)lo.w;
            f[4] = (__bf16)hi.x; f[5] = (__bf16)hi.y; f[6] = (__bf16)hi.z; f[7] = (__bf16)hi.w;
            wfrag[kt] = f;
        }
    }
    const float bias_n = bias[wrow];

    // elementwise identity: lane -> (batch eb, dim 4*wave+edd)
    const int eb = lane & 15;
    const int edd = lane >> 4;
    const int dim_local_e = (wave << 2) + edd;
    const int bg_e = grp * 16 + eb;
    float c_state = 0.f;

    // staging identity
    const int sb = tid >> 4;    // batch 0..15
    const int sseg = tid & 15;  // 16 segments per row

    auto stage_x = [&](int t) {
        if constexpr (L0) {
            const float* p = xf + ((long)(grp * 16 + sb) * T_STEPS + t) * 128 + sseg * 8;
            float4 lo = *(const float4*)p;
            float4 hi = *(const float4*)(p + 4);
            u16x8 v;
            v[0] = f2bf(lo.x); v[1] = f2bf(lo.y); v[2] = f2bf(lo.z); v[3] = f2bf(lo.w);
            v[4] = f2bf(hi.x); v[5] = f2bf(hi.y); v[6] = f2bf(hi.z); v[7] = f2bf(hi.w);
            *(u16x8*)&A_lds[sb * LDA + 256 + sseg * 8] = v;
        } else {
            const u16* p = xb + ((long)t * 64 + grp * 16 + sb) * 256 + sseg * 16;
            u16x8 v0 = *(const u16x8*)p;
            u16x8 v1 = *(const u16x8*)(p + 8);
            *(u16x8*)&A_lds[sb * LDA + 256 + sseg * 16] = v0;
            *(u16x8*)&A_lds[sb * LDA + 256 + sseg * 16 + 8] = v1;
        }
    };

    bf16x8 xfrag[NXF];
    auto read_xfrags = [&] {
#pragma unroll
        for (int kt = 0; kt < NXF; ++kt)
            xfrag[kt] = __builtin_bit_cast(
                bf16x8, *(const u16x8*)&A_lds[n * LDA + 256 + kt * 32 + g * 8]);
    };

    // prologue: x(0)
    stage_x(0);
    __syncthreads();
    read_xfrags();

    bool dead = false;
    for (int s = 0; s < T_STEPS; ++s) {
        // ---- wait for h(s) from all 16 blocks of this group ----
        if (s > 0) {
            if (tid == 0) {
                u32* cp = ctr + (grp * 513 + s) * CTR_STRIDE;
                if (!dead) {
                    int guard = 0;
                    while (__hip_atomic_load(cp, __ATOMIC_RELAXED, __HIP_MEMORY_SCOPE_AGENT) < GQ) {
                        __builtin_amdgcn_s_sleep(1);
                        if (++guard > (1 << 20)) { dead = true; break; }
                    }
                }
                __threadfence();  // acquire: inv L1 (+cross-XCD L2 lines)
            }
            __syncthreads();
        }

        // ---- stage h(s) into A_lds; x-part MFMAs hide the global load latency ----
        const int rp = s & 1;
        f32x4 acc = {bias_n, bias_n, bias_n, bias_n};
        {
            const u16* p = hbuf + ((rp * NGRP + grp) * 16 + sb) * 256 + sseg * 16;
            u16x8 h0 = *(const u16x8*)p;
            u16x8 h1 = *(const u16x8*)(p + 8);
#pragma unroll
            for (int kt = 0; kt < NXF; ++kt)
                acc = __builtin_amdgcn_mfma_f32_16x16x32_bf16(xfrag[kt], wfrag[NHF + kt], acc, 0, 0, 0);
            *(u16x8*)&A_lds[sb * LDA + sseg * 16] = h0;
            *(u16x8*)&A_lds[sb * LDA + sseg * 16 + 8] = h1;
        }
        __syncthreads();

        // ---- recurrent MFMAs (K=256 from LDS) ----
#pragma unroll
        for (int kt = 0; kt < NHF; ++kt) {
            bf16x8 af = __builtin_bit_cast(
                bf16x8, *(const u16x8*)&A_lds[n * LDA + kt * 32 + g * 8]);
            acc = __builtin_amdgcn_mfma_f32_16x16x32_bf16(af, wfrag[kt], acc, 0, 0, 0);
        }

        // ---- D -> wave-local LDS, regroup so each lane owns (batch, dim) with all 4 gates ----
#pragma unroll
        for (int r = 0; r < 4; ++r)
            D_lds[wave * 272 + n * 17 + g * 4 + r] = acc[r];
        float ga[4];
#pragma unroll
        for (int aa = 0; aa < 4; ++aa)
            ga[aa] = D_lds[wave * 272 + (aa * 4 + edd) * 17 + eb];

        // ---- elementwise (gate order: f, i, o, g) ----
        float fg = sigm(ga[0]);
        float ig = sigm(ga[1]);
        float og = sigm(ga[2]);
        float gg = tanh_(ga[3]);
        c_state = fg * c_state + ig * gg;
        float h_new = og * tanh_(c_state);
        h_slice[eb * 16 + dim_local_e] = f2bf(h_new);

        if (s == T_STEPS - 1) {
            const int o1 = bg_e * 256 + q * 16 + dim_local_e;
            if constexpr (L0) {
                out[16384 + o1] = h_new;   // h_n[0]
                out[49152 + o1] = c_state; // c_n[0]
            } else {
                out[o1] = h_new;           // h1T
                out[32768 + o1] = h_new;   // h_n[1]
                out[65536 + o1] = c_state; // c_n[1]
            }
        }
        __syncthreads();

        // ---- publish h(s+1) ----
        const int wp = (s + 1) & 1;
        if (tid < 16) {
            u16x8 v0 = *(const u16x8*)&h_slice[tid * 16];
            u16x8 v1 = *(const u16x8*)&h_slice[tid * 16 + 8];
            u16* p = hbuf + ((wp * NGRP + grp) * 16 + tid) * 256 + q * 16;
            *(u16x8*)p = v0;
            *(u16x8*)(p + 8) = v1;
        } else if (L0 && tid < 32) {
            const int b2 = tid - 16;
            u16x8 v0 = *(const u16x8*)&h_slice[b2 * 16];
            u16x8 v1 = *(const u16x8*)&h_slice[b2 * 16 + 8];
            u16* p = hs0 + ((long)s * 64 + grp * 16 + b2) * 256 + q * 16;
            *(u16x8*)p = v0;
            *(u16x8*)(p + 8) = v1;
        }
        __syncthreads();  // drains stores (vmcnt 0) so tid0's release covers them

        if (tid == 0) {
            __hip_atomic_fetch_add(ctr + (grp * 513 + (s + 1)) * CTR_STRIDE, 1u,
                                   __ATOMIC_RELEASE, __HIP_MEMORY_SCOPE_AGENT);
        }

        // ---- prefetch x(s+1) while other blocks finish ----
        if (s + 1 < T_STEPS) {
            stage_x(s + 1);
            __syncthreads();
            read_xfrags();
        }
    }
}

extern "C" void kernel_launch(void* const* d_in, const int* in_sizes, int n_in,
                              void* d_out, int out_size, void* d_ws, size_t ws_size,
                              hipStream_t stream) {
    (void)in_sizes; (void)n_in; (void)out_size;
    const float* x  = (const float*)d_in[0];
    const float* W0 = (const float*)d_in[1];
    const float* b0 = (const float*)d_in[2];
    const float* W1 = (const float*)d_in[3];
    const float* b1 = (const float*)d_in[4];
    float* out = (float*)d_out;

    char* ws = (char*)d_ws;
    u32* ctr0 = (u32*)ws;
    u32* ctr1 = ctr0 + CTR_U32_PER_LAYER;
    u16* hbuf0 = (u16*)(ws + HBUF_OFF_BYTES);
    u16* hbuf1 = hbuf0 + HBUF_U16_PER_LAYER;
    u16* hs0 = (u16*)(ws + HS0_OFF_BYTES);

    const size_t needed = (size_t)HS0_OFF_BYTES + (size_t)512 * 64 * 256 * 2;
    if (ws_size < needed) return;  // workspace too small; fail loudly (zeros)

    // re-zero sync counters + h double-buffers every call (replay-deterministic)
    hipMemsetAsync(d_ws, 0, HBUF_OFF_BYTES + (size_t)2 * HBUF_U16_PER_LAYER * 2, stream);

    lstm_rec<128, true ><<<64, 256, 0, stream>>>(x, nullptr, W0, b0, ctr0, hbuf0, hs0, out);
    lstm_rec<256, false><<<64, 256, 0, stream>>>(nullptr, hs0, W1, b1, ctr1, hbuf1, hs0, out);
}

// Round 2
// 2285.084 us; speedup vs baseline: 1.8497x; 1.8497x over previous
//
#include <hip/hip_runtime.h>
#include <hip/hip_bf16.h>
#include <cstdint>

typedef unsigned int u32;
typedef unsigned short u16;
typedef __bf16 bf16x8 __attribute__((ext_vector_type(8)));
typedef float f32x4 __attribute__((ext_vector_type(4)));
typedef u16 u16x8 __attribute__((ext_vector_type(8)));

#define T_STEPS 512
#define NGRP 4            // batch groups (16 batches each)
#define GQ 16             // blocks per group per layer (each owns 16 h-dims)
#define FLAG_STRIDE 16    // u32 per flag line (64B)

#define FLAGS_BYTES (2 * NGRP * GQ * FLAG_STRIDE * 4)   // 8 KB
#define HBUF_U32_PER_LAYER (2 * NGRP * 16 * 128)        // [parity][grp][b][128 u32]
#define HS0_OFF_BYTES (1u << 20)

__device__ __forceinline__ float sigm(float z) { return 1.f / (1.f + __expf(-z)); }
__device__ __forceinline__ float tanh_(float z) { return 1.f - 2.f / (__expf(2.f * z) + 1.f); }
__device__ __forceinline__ u16 f2bf(float f) {
    union { __bf16 b; u16 u; } v; v.b = (__bf16)f; return v.u;
}

// Relaxed agent-scope atomics: coherent at the agent point (no L1/L2 staleness),
// crucially WITHOUT the L2 writeback/invalidate sweeps that acq/rel fences emit.
__device__ __forceinline__ u32 gload(const u32* p) {
    return __hip_atomic_load(p, __ATOMIC_RELAXED, __HIP_MEMORY_SCOPE_AGENT);
}
__device__ __forceinline__ void gstore(u32* p, u32 v) {
    __hip_atomic_store(p, v, __ATOMIC_RELAXED, __HIP_MEMORY_SCOPE_AGENT);
}
__device__ __forceinline__ void drain_vm() {
    asm volatile("s_waitcnt vmcnt(0)" ::: "memory");
}

// Block (layer, grp, q): batches [16*grp,16*grp+16), h-dims [16*q,16*q+16).
// 256 threads = 4 waves; wave w owns dims [4w,4w+4) x 4 gates (one 16-wide MFMA N-tile).
template <int KX, bool L0>
__device__ void lstm_body(
    int grp, int q,
    const float* __restrict__ xf,   // layer0 input x [64][512][128] f32
    const float* __restrict__ W,    // [1024][256+KX] f32 (cols: [h | x])
    const float* __restrict__ bias, // [1024]
    u32* __restrict__ flags,        // [2][NGRP][GQ] monotone step flags (stride 16 u32)
    u32* __restrict__ hbuf,         // this layer: [2][grp][16][128] u32 (bf16 pairs)
    u32* __restrict__ hs0,          // [512][64][128] u32 (bf16 pairs)
    float* __restrict__ out,
    u16* A_lds, float* D_lds, u16* h_slice)
{
    constexpr int K = 256 + KX;
    constexpr int NHF = 8;          // h-part k-tiles (K=32 each)
    constexpr int NXF = KX / 32;    // x-part k-tiles
    constexpr int LDA = K + 8;      // u16 per A_lds row (pad)

    const int tid = threadIdx.x;
    const int wave = tid >> 6;
    const int lane = tid & 63;
    const int g = lane >> 4;
    const int n = lane & 15;

    // ---- weights -> register B-fragments (one-time) ----
    const int a_gate = n >> 2;
    const int dd = n & 3;
    const int wrow = a_gate * 256 + q * 16 + (wave << 2) + dd;
    bf16x8 wfrag[K / 32];
    {
        const float* Wr = W + (long)wrow * K;
#pragma unroll
        for (int kt = 0; kt < K / 32; ++kt) {
            const float* p = Wr + kt * 32 + g * 8;
            float4 lo = *(const float4*)p;
            float4 hi = *(const float4*)(p + 4);
            bf16x8 f;
            f[0] = (__bf16)lo.x; f[1] = (__bf16)lo.y; f[2] = (__bf16)lo.z; f[3] = (__bf16)lo.w;
            f[4] = (__bf16)hi.x; f[5] = (__bf16)hi.y; f[6] = (__bf16)hi.z; f[7] = (__bf16)hi.w;
            wfrag[kt] = f;
        }
    }
    const float bias_n = bias[wrow];

    // elementwise identity
    const int eb = lane & 15;
    const int edd = lane >> 4;
    const int dim_local_e = (wave << 2) + edd;
    const int bg_e = grp * 16 + eb;
    float c_state = 0.f;

    // staging identity
    const int sb = tid >> 4;    // batch 0..15
    const int sseg = tid & 15;  // segment

    // flag pointers
    const int layer = L0 ? 0 : 1;
    u32* myflag = flags + (((layer * NGRP + grp) * GQ) + q) * FLAG_STRIDE;
    u32* poll_p = nullptr;
    int poll_delta = 0;
    bool poll_active = false;
    if (wave == 0) {
        if (L0) {
            if (lane < 16) { poll_p = flags + ((0 * NGRP + grp) * GQ + lane) * FLAG_STRIDE; poll_active = true; poll_delta = 0; }
        } else {
            if (lane < 16)      { poll_p = flags + ((0 * NGRP + grp) * GQ + lane) * FLAG_STRIDE; poll_active = true; poll_delta = 1; }  // L0 hs0(t) ready
            else if (lane < 32) { poll_p = flags + ((1 * NGRP + grp) * GQ + (lane - 16)) * FLAG_STRIDE; poll_active = true; poll_delta = 0; }  // peers h(t)
        }
    }

    auto stage_x = [&](int t) {
        if constexpr (L0) {
            const float* p = xf + ((long)(grp * 16 + sb) * T_STEPS + t) * 128 + sseg * 8;
            float4 lo = *(const float4*)p;
            float4 hi = *(const float4*)(p + 4);
            u16x8 v;
            v[0] = f2bf(lo.x); v[1] = f2bf(lo.y); v[2] = f2bf(lo.z); v[3] = f2bf(lo.w);
            v[4] = f2bf(hi.x); v[5] = f2bf(hi.y); v[6] = f2bf(hi.z); v[7] = f2bf(hi.w);
            *(u16x8*)&A_lds[sb * LDA + 256 + sseg * 8] = v;
        }
    };

    bf16x8 xfrag[NXF > 0 ? NXF : 1];
    auto read_xfrags = [&] {
        if constexpr (L0) {
#pragma unroll
            for (int kt = 0; kt < NXF; ++kt)
                xfrag[kt] = __builtin_bit_cast(
                    bf16x8, *(const u16x8*)&A_lds[n * LDA + 256 + kt * 32 + g * 8]);
        }
    };

    if constexpr (L0) {
        stage_x(0);
        __syncthreads();
        read_xfrags();
    }

    bool dead = false;
    for (int s = 0; s < T_STEPS; ++s) {
        // ---- wait: peers' h(s) ready (and for L1: layer0's hs0(s)) ----
        if (wave == 0) {
            const u32 tgt = (u32)(s + poll_delta);
            const bool need = poll_active && tgt > 0 && !dead;
            if (__any((int)need)) {
                int guard = 0;
                while (true) {
                    bool ok = !need || (gload(poll_p) >= tgt);
                    if (__all((int)ok)) break;
                    if (++guard > (1 << 19)) { dead = true; break; }
                }
            }
        }
        __syncthreads();

        // ---- load h(s) (+ hs0(s) for L1) via agent-coherent loads; stage to LDS ----
        const int rp = s & 1;
        f32x4 acc = {bias_n, bias_n, bias_n, bias_n};
        u32 hv[8];
        {
            const u32* hp = hbuf + (((size_t)rp * NGRP + grp) * 16 + sb) * 128 + sseg * 8;
#pragma unroll
            for (int j = 0; j < 8; ++j) hv[j] = gload(hp + j);
        }
        u32 xv[8];
        if constexpr (!L0) {
            const u32* xp = hs0 + (((size_t)s * 64) + grp * 16 + sb) * 128 + sseg * 8;
#pragma unroll
            for (int j = 0; j < 8; ++j) xv[j] = gload(xp + j);
        }
        if constexpr (L0) {
            // x-part MFMAs (xfrag prefetched) hide the h-load latency
#pragma unroll
            for (int kt = 0; kt < NXF; ++kt)
                acc = __builtin_amdgcn_mfma_f32_16x16x32_bf16(xfrag[kt], wfrag[NHF + kt], acc, 0, 0, 0);
        }
        {
            u32* Arow = (u32*)&A_lds[sb * LDA];
#pragma unroll
            for (int j = 0; j < 8; ++j) Arow[sseg * 8 + j] = hv[j];
            if constexpr (!L0) {
#pragma unroll
                for (int j = 0; j < 8; ++j) Arow[128 + sseg * 8 + j] = xv[j];
            }
        }
        __syncthreads();

        // ---- recurrent MFMAs from LDS ----
        constexpr int NLDS = L0 ? NHF : (NHF + NXF);
#pragma unroll
        for (int kt = 0; kt < NLDS; ++kt) {
            bf16x8 af = __builtin_bit_cast(
                bf16x8, *(const u16x8*)&A_lds[n * LDA + kt * 32 + g * 8]);
            acc = __builtin_amdgcn_mfma_f32_16x16x32_bf16(af, wfrag[kt], acc, 0, 0, 0);
        }

        // ---- regroup D via wave-local LDS: lane -> (batch, dim) holding 4 gates ----
#pragma unroll
        for (int r = 0; r < 4; ++r)
            D_lds[wave * 272 + n * 17 + g * 4 + r] = acc[r];
        float ga[4];
#pragma unroll
        for (int aa = 0; aa < 4; ++aa)
            ga[aa] = D_lds[wave * 272 + (aa * 4 + edd) * 17 + eb];

        // ---- elementwise (gate order: f, i, o, g) ----
        float fg = sigm(ga[0]);
        float ig = sigm(ga[1]);
        float og = sigm(ga[2]);
        float gg = tanh_(ga[3]);
        c_state = fg * c_state + ig * gg;
        float h_new = og * tanh_(c_state);
        h_slice[eb * 16 + dim_local_e] = f2bf(h_new);

        if (s == T_STEPS - 1) {
            const int o1 = bg_e * 256 + q * 16 + dim_local_e;
            if constexpr (L0) {
                out[16384 + o1] = h_new;   // h_n[0]
                out[49152 + o1] = c_state; // c_n[0]
            } else {
                out[o1] = h_new;           // h1T
                out[32768 + o1] = h_new;   // h_n[1]
                out[65536 + o1] = c_state; // c_n[1]
            }
        }
        __syncthreads();

        // ---- publish h(s+1) (+ hs0(s) for L0) with agent-coherent stores ----
        const int wp = (s + 1) & 1;
        if (tid < 16) {
            const u32* hrow = (const u32*)&h_slice[tid * 16];
            u32* p = hbuf + (((size_t)wp * NGRP + grp) * 16 + tid) * 128 + q * 8;
#pragma unroll
            for (int j = 0; j < 8; ++j) gstore(p + j, hrow[j]);
        } else if (L0 && tid < 32) {
            const int b2 = tid - 16;
            const u32* hrow = (const u32*)&h_slice[b2 * 16];
            u32* p = hs0 + (((size_t)s * 64) + grp * 16 + b2) * 128 + q * 8;
#pragma unroll
            for (int j = 0; j < 8; ++j) gstore(p + j, hrow[j]);
        }
        if (wave == 0) {
            drain_vm();                       // data stores reach coherence point
            if (lane == 0) gstore(myflag, (u32)(s + 1));  // then release the step
        }

        // ---- prefetch x(s+1) while others finish ----
        if constexpr (L0) {
            if (s + 1 < T_STEPS) stage_x(s + 1);
        }
        __syncthreads();
        read_xfrags();
    }
}

__global__ __launch_bounds__(256, 1) void lstm_fused(
    const float* __restrict__ xf,
    const float* __restrict__ W0, const float* __restrict__ b0,
    const float* __restrict__ W1, const float* __restrict__ b1,
    u32* __restrict__ flags,
    u32* __restrict__ hbuf0, u32* __restrict__ hbuf1,
    u32* __restrict__ hs0,
    float* __restrict__ out)
{
    __shared__ u16 A_lds[16 * 520];        // max LDA = 512+8
    __shared__ float D_lds[4 * 16 * 17];
    __shared__ u16 h_slice[16 * 16];

    const int bid = blockIdx.x;
    if (bid < 64) {
        lstm_body<128, true >(bid >> 4, bid & 15, xf, W0, b0, flags, hbuf0, hs0, out,
                              A_lds, D_lds, h_slice);
    } else {
        const int b2 = bid - 64;
        lstm_body<256, false>(b2 >> 4, b2 & 15, nullptr, W1, b1, flags, hbuf1, hs0, out,
                              A_lds, D_lds, h_slice);
    }
}

extern "C" void kernel_launch(void* const* d_in, const int* in_sizes, int n_in,
                              void* d_out, int out_size, void* d_ws, size_t ws_size,
                              hipStream_t stream) {
    (void)in_sizes; (void)n_in; (void)out_size;
    const float* x  = (const float*)d_in[0];
    const float* W0 = (const float*)d_in[1];
    const float* b0 = (const float*)d_in[2];
    const float* W1 = (const float*)d_in[3];
    const float* b1 = (const float*)d_in[4];
    float* out = (float*)d_out;

    char* ws = (char*)d_ws;
    u32* flags = (u32*)ws;
    u32* hbuf0 = (u32*)(ws + FLAGS_BYTES);
    u32* hbuf1 = hbuf0 + HBUF_U32_PER_LAYER;
    u32* hs0 = (u32*)(ws + HS0_OFF_BYTES);

    const size_t needed = (size_t)HS0_OFF_BYTES + (size_t)512 * 64 * 256 * 2;
    if (ws_size < needed) return;

    // zero flags + both h double-buffers (h(0)=0) each call — replay-deterministic
    hipMemsetAsync(d_ws, 0, FLAGS_BYTES + (size_t)2 * HBUF_U32_PER_LAYER * 4, stream);

    lstm_fused<<<128, 256, 0, stream>>>(x, W0, b0, W1, b1, flags, hbuf0, hbuf1, hs0, out);
}